// Round 2
// baseline (858.686 us; speedup 1.0000x reference)
//
#include <hip/hip_runtime.h>
#include <math.h>

// Masked similar-user attention: out[b,s,d] = softmax_u(mask? -1e9 : cu[b]·sue[b,s,u]) · sue[b,s,u,d] + cie[b,s,d]
//
// R2: persistent waves + register double-buffered prefetch.
// One wave per (b,s) tile, 16 tiles per wave (6400 waves total). Each
// iteration issues the NEXT tile's global loads before computing the current
// tile, keeping ~14 loads in flight through the shfl-reduction tail so the
// memory pipe never drains (R1 was latency/pipelining-bound: no intra-wave
// overlap between tile t compute and tile t+1 loads).
//
// Lane layout per tile (50x32 fp32 = 400 float4): lane l, chunk j holds
// float4 at tile element j*256+4l  =>  u = 8j + (l>>3), d = 4*(l&7).
// j=0..6 covers u in [0,56); u>=50 is padding (score = -inf -> weight 0).

#define NEG_INF_F (-1e9f)

constexpr int B = 512, S = 200, U = 50, D = 32;
constexpr int TILES = B * S;                      // 102400
constexpr int TILE_F4 = U * D / 4;                // 400 float4 per tile
constexpr int SUE_F4 = TILES * TILE_F4;           // 40,960,000 float4 total

constexpr int BLOCKS = 1600;
constexpr int NWAVES = BLOCKS * 4;                // 6400 -> exactly 16 tiles/wave

struct TileBuf {
    float4 v[7];   // sue fragments
    int    mk[7];  // mask bits (1 for padding u>=50, but padding handled by u check)
    float4 c4;     // current-user fragment
    float4 ci;     // current-item fragment
};

__device__ __forceinline__ void prefetch_tile(
    int tile, int lane, int g, int d0,
    const float4* __restrict__ sue4, const float* __restrict__ cu,
    const float* __restrict__ cie, const int* __restrict__ mask,
    TileBuf& tb)
{
    const int base4 = tile * TILE_F4;
    #pragma unroll
    for (int j = 0; j < 7; ++j) {
        int gi = base4 + j * 64 + lane;
        gi = min(gi, SUE_F4 - 1);                 // clamp padding over-read (last tile only)
        tb.v[j] = sue4[gi];
    }
    const int mrow = tile * U;
    #pragma unroll
    for (int j = 0; j < 7; ++j) {
        const int u = j * 8 + g;
        tb.mk[j] = (u < U) ? mask[mrow + u] : 1;
    }
    const int b = tile / S;
    tb.c4 = *(const float4*)(cu + b * D + d0);
    tb.ci = *(const float4*)(cie + tile * D + d0);
}

__device__ __forceinline__ void compute_tile(
    int tile, int g, int d0, const TileBuf& tb, float* __restrict__ out)
{
    // ---- scores: per-lane partial dot, reduce over d via xor 1/2/4 ----
    float sc[7];
    #pragma unroll
    for (int j = 0; j < 7; ++j) {
        float p = tb.v[j].x * tb.c4.x + tb.v[j].y * tb.c4.y
                + tb.v[j].z * tb.c4.z + tb.v[j].w * tb.c4.w;
        p += __shfl_xor(p, 1);
        p += __shfl_xor(p, 2);
        p += __shfl_xor(p, 4);
        const int u = j * 8 + g;
        if (u >= U)        p = -INFINITY;         // padding: true exclude
        else if (tb.mk[j]) p = NEG_INF_F;         // reference's finite -1e9
        sc[j] = p;
    }

    // ---- softmax over u: reduce across the 8 u-subgroups via xor 8/16/32 ----
    float m = sc[0];
    #pragma unroll
    for (int j = 1; j < 7; ++j) m = fmaxf(m, sc[j]);
    m = fmaxf(m, __shfl_xor(m, 8));
    m = fmaxf(m, __shfl_xor(m, 16));
    m = fmaxf(m, __shfl_xor(m, 32));

    float e[7];
    float tsum = 0.f;
    #pragma unroll
    for (int j = 0; j < 7; ++j) {
        e[j] = __expf(sc[j] - m);                 // -inf -> 0; all-masked row -> uniform 1/50
        tsum += e[j];
    }
    tsum += __shfl_xor(tsum, 8);
    tsum += __shfl_xor(tsum, 16);
    tsum += __shfl_xor(tsum, 32);
    const float inv = 1.0f / tsum;

    // ---- weighted sum over u (values in registers) ----
    float4 o = make_float4(0.f, 0.f, 0.f, 0.f);
    #pragma unroll
    for (int j = 0; j < 7; ++j) {
        const float a = e[j] * inv;
        o.x += a * tb.v[j].x; o.y += a * tb.v[j].y;
        o.z += a * tb.v[j].z; o.w += a * tb.v[j].w;
    }
    #pragma unroll
    for (int msk = 8; msk <= 32; msk <<= 1) {
        o.x += __shfl_xor(o.x, msk);
        o.y += __shfl_xor(o.y, msk);
        o.z += __shfl_xor(o.z, msk);
        o.w += __shfl_xor(o.w, msk);
    }

    // ---- residual + store (lanes 0..7 write 128B contiguous) ----
    if (g == 0) {
        float4 r = make_float4(o.x + tb.ci.x, o.y + tb.ci.y,
                               o.z + tb.ci.z, o.w + tb.ci.w);
        *(float4*)(out + tile * D + d0) = r;
    }
}

__global__ __launch_bounds__(256) void DIB_69861938037647_kernel(
    const float* __restrict__ cu,    // [B, D]
    const float* __restrict__ sue,   // [B, S, U, D]
    const float* __restrict__ cie,   // [B, S, D]
    const int*   __restrict__ mask,  // [B, S, U]  nonzero = masked out
    float* __restrict__ out)         // [B, S, D]
{
    const int lane = threadIdx.x & 63;
    const int wid  = (blockIdx.x << 2) + (threadIdx.x >> 6);
    const int g    = lane >> 3;                   // u subgroup 0..7
    const int d0   = (lane & 7) * 4;              // d offset 0,4,...,28

    const float4* sue4 = (const float4*)sue;

    TileBuf bufA, bufB;
    int t = wid;
    prefetch_tile(t, lane, g, d0, sue4, cu, cie, mask, bufA);

    // 16 tiles per wave = 8 software-pipelined pairs.
    #pragma unroll 1
    for (int it = 0; it < 8; ++it) {
        const int t1 = t + NWAVES;                // always < TILES (exact division)
        prefetch_tile(t1, lane, g, d0, sue4, cu, cie, mask, bufB);
        compute_tile(t, g, d0, bufA, out);

        const int t2 = t1 + NWAVES;
        if (t2 < TILES)                           // false only on the final pair (uniform)
            prefetch_tile(t2, lane, g, d0, sue4, cu, cie, mask, bufA);
        compute_tile(t1, g, d0, bufB, out);
        t = t2;
    }
}

extern "C" void kernel_launch(void* const* d_in, const int* in_sizes, int n_in,
                              void* d_out, int out_size, void* d_ws, size_t ws_size,
                              hipStream_t stream) {
    const float* cu   = (const float*)d_in[0];
    const float* sue  = (const float*)d_in[1];
    const float* cie  = (const float*)d_in[2];
    const int*   mask = (const int*)d_in[3];
    float* out = (float*)d_out;

    DIB_69861938037647_kernel<<<BLOCKS, 256, 0, stream>>>(cu, sue, cie, mask, out);
}